// Round 12
// baseline (144.177 us; speedup 1.0000x reference)
//
#include <hip/hip_runtime.h>
#include <math.h>

// Problem constants
#define BATCH 8192
#define LOD 60
#define LSD 120
#define AD 10
#define NB 15
#define BW 3
#define H 60

// Output layout (floats)
#define NM_SZ (BATCH * LSD)   // next_mean 983040
#define NC_SZ (BATCH * LOD)   // 491520 each for ncu/ncl/ncs

// Workspace layout (floats):
//   tmbg  @ 0      : [60][448] banded tm pack (64B-aligned rows for s_load)
//   coef_t@ 26880  : [15][8192] softmaxed mixture coefs, transposed
//   ctrl_t@ 149760 : [120][8192] control rows, transposed
#define TMBG_STRIDE 448
#define TMBG_ROW 420                      // NB*7*4 valid floats per row
#define TMBG_FLOATS (LOD * TMBG_STRIDE)   // 26880 = 105 * 256
#define WS_COEF TMBG_FLOATS
#define WS_CTRL (WS_COEF + NB * BATCH)    // 149760

// Main-kernel geometry: 128 bg (64 batches) x 8 rg (8 rows) = 1024 blocks.
#define RGS 8
#define RG_ROWS 8
#define OST_PLANE (RG_ROWS * 65)      // 520; LDS = ost only (2600 f = 10.4 KB)

typedef float v2f __attribute__((ext_vector_type(2)));
#define FMA2(a, b, c) __builtin_elementwise_fma((a), (b), (c))

__device__ __forceinline__ float elup1f(float x) {
    return x < 0.0f ? __expf(x) : x + 1.0f;
}

// ---------------------------------------------------------------------------
// Prepass: blocks [0,1024): MLP for 8 batches each (high TLP: ~4 blocks/CU);
//          blocks [1024,1129): banded tm pack (105*256 = 26880 exactly).
// All barriers are outside thread guards; pack blocks return before any.
// ---------------------------------------------------------------------------
__global__ __launch_bounds__(256) void k_prep(
    const float* __restrict__ pm, const float* __restrict__ action,
    const float* __restrict__ tm11, const float* __restrict__ tm12,
    const float* __restrict__ tm21, const float* __restrict__ tm22,
    const float* __restrict__ w_coef, const float* __restrict__ b_coef,
    const float* __restrict__ w_c1, const float* __restrict__ b_c1,
    const float* __restrict__ w_c2, const float* __restrict__ b_c2,
    float* __restrict__ ws)
{
    const int tid = threadIdx.x;
    const int bid = blockIdx.x;

    if (bid >= 1024) {                   // ---- banded tm pack ----
        int idx = (bid - 1024) * 256 + tid;
        if (idx < TMBG_FLOATS) {
            int i = idx / TMBG_STRIDE;
            int r = idx - i * TMBG_STRIDE;
            float val = 0.0f;
            if (r < TMBG_ROW) {
                int k  = r / 28;
                int z  = r - k * 28;
                int jo = z >> 2;
                int m  = z & 3;
                int j  = i - BW + jo;
                const float* tmm = (m == 0) ? tm11 : (m == 1) ? tm12
                                 : (m == 2) ? tm21 : tm22;
                if (j >= 0 && j < LOD) val = tmm[k * (LOD * LOD) + i * LOD + j];
            }
            ws[idx] = val;
        }
        return;                          // block-uniform early exit
    }

    // ---- MLP for 8 batches ----
    __shared__ float pm_s[LSD * 9];      // [j][b], stride 9: 1080 f
    __shared__ float lg_s[8 * 16];       // [b][k]
    __shared__ float hid_s[H * 9];       // [h][b], stride 9: 540 f

    const int b0 = bid * 8;

    // stage pm (coalesced read, stride-9 LDS write)
    for (int idx = tid; idx < 8 * LSD; idx += 256) {
        int b = idx / LSD, j = idx - b * LSD;
        pm_s[j * 9 + b] = pm[(size_t)(b0 + b) * LSD + j];
    }
    // hidden (global action only; overlaps with staging latency)
    if (tid < 240) {                     // h0 = tid>>3 (0..29), b = tid&7
        int h0 = tid >> 3, b = tid & 7;
        const float* ar = action + (size_t)(b0 + b) * AD;
        float av[AD];
        #pragma unroll
        for (int a = 0; a < AD; ++a) av[a] = ar[a];
        float acc0 = b_c1[h0], acc1 = b_c1[h0 + 30];
        #pragma unroll
        for (int a = 0; a < AD; ++a) {
            acc0 = fmaf(av[a], w_c1[h0 * AD + a], acc0);
            acc1 = fmaf(av[a], w_c1[(h0 + 30) * AD + a], acc1);
        }
        hid_s[h0 * 9 + b]        = fmaxf(acc0, 0.0f);
        hid_s[(h0 + 30) * 9 + b] = fmaxf(acc1, 0.0f);
    }
    __syncthreads();   // bar1: pm_s + hid_s ready

    // logits: tid<120: k = tid>>3 (0..14), b = tid&7
    if (tid < 120) {
        int k = tid >> 3, b = tid & 7;
        const float* wk = w_coef + k * LSD;     // L1-resident (7 KB total)
        float acc = b_coef[k];
        #pragma unroll 4
        for (int j = 0; j < LSD; ++j)
            acc = fmaf(pm_s[j * 9 + b], wk[j], acc);
        lg_s[b * 16 + k] = acc;
    }
    __syncthreads();   // bar2: logits ready

    // softmax: tid<8 (b = tid)
    if (tid < 8) {
        float v[NB];
        float mx = -1e30f;
        #pragma unroll
        for (int k = 0; k < NB; ++k) { v[k] = lg_s[tid * 16 + k]; mx = fmaxf(mx, v[k]); }
        float sm = 0.0f;
        #pragma unroll
        for (int k = 0; k < NB; ++k) { v[k] = __expf(v[k] - mx); sm += v[k]; }
        float inv = 1.0f / sm;
        #pragma unroll
        for (int k = 0; k < NB; ++k)
            ws[WS_COEF + k * BATCH + b0 + tid] = v[k] * inv;
    }
    // control: b = tid&7, og = tid>>3 (0..31); o = og + 32r, r<4, skip o>=120
    {
        const int b = tid & 7, og = tid >> 3;
        #pragma unroll
        for (int r = 0; r < 4; ++r) {
            int o = og + 32 * r;
            if (o < 120) {
                const float* wr = w_c2 + o * H;  // L1-resident (28.8 KB total)
                float acc = b_c2[o];
                #pragma unroll 4
                for (int h = 0; h < H; ++h)
                    acc = fmaf(hid_s[h * 9 + b], wr[h], acc);
                ws[WS_CTRL + (size_t)o * BATCH + b0 + b] = acc;
            }
        }
    }
}

// ---------------------------------------------------------------------------
// Main kernel: banded predict. Window values loaded DIRECTLY to registers
// (L2-hot via XCD swizzle; no vs staging, 1 barrier). MLP results from ws
// coalesced; mixing weights via uniform scalar loads (SMEM pipe).
// ---------------------------------------------------------------------------
__global__ __launch_bounds__(256, 4) void k_main(
    const float* __restrict__ pm, const float* __restrict__ cu,
    const float* __restrict__ cl, const float* __restrict__ cs,
    const float* __restrict__ log_noise,
    const float* __restrict__ ws,        // tmbg / coef_t / ctrl_t
    float* __restrict__ out)
{
    __shared__ float ost[5 * OST_PLANE];   // 10.4 KB (only LDS here)

    const int tid  = threadIdx.x;
    const int lane = tid & 63;
    const int wv   = __builtin_amdgcn_readfirstlane(tid >> 6);

    // XCD-grouped swizzle: the 8 rg-blocks of one bg share one XCD's L2.
    const int bid  = blockIdx.x;            // 1024 = 8 XCDs * 128
    const int xcd  = bid & 7;
    const int slot = bid >> 3;              // 0..127
    const int bg   = xcd * 16 + (slot >> 3);
    const int rg   = slot & 7;
    const int b0   = bg * 64;
    const int i0   = rg * RG_ROWS;
    const int b    = b0 + lane;

    const float* coef_t = ws + WS_COEF;
    const float* ctrl_t = ws + WS_CTRL;

    // ---------------- issue ALL global loads up front (T14) ----------------
    float cf[NB];
    #pragma unroll
    for (int k = 0; k < NB; ++k) cf[k] = coef_t[k * BATCH + b];   // coalesced

    const int r0g = i0 + 2 * wv;
    const int c0  = (r0g < LOD) ? r0g : LOD - 1;        // rg7/wv3 clamp
    const int c1  = (r0g + 1 < LOD) ? r0g + 1 : LOD - 1;
    float ctl0 = ctrl_t[c0 * BATCH + b];                 // coalesced
    float ctl1 = ctrl_t[c1 * BATCH + b];
    float ctl2 = ctrl_t[(LOD + c0) * BATCH + b];
    float ctl3 = ctrl_t[(LOD + c1) * BATCH + b];

    // window: j = i0 + 2wv - 3 + z, z = 0..7 (covers both rows' bands);
    // per-lane own-row scalars, L2-hot (tile re-read by 8 rg-blocks/XCD)
    float w_m[8], w_n[8], w_u[8], w_l[8], w_s[8];
    {
        const int jb = i0 + 2 * wv - BW;
        const float* pmr = pm + (size_t)b * LSD;
        const float* cur = cu + (size_t)b * LOD;
        const float* clr = cl + (size_t)b * LOD;
        const float* csr = cs + (size_t)b * LOD;
        #pragma unroll
        for (int z = 0; z < 8; ++z) {
            int j = jb + z;
            bool ok = (j >= 0) && (j < LOD);
            int jc = ok ? j : 0;
            float mm = pmr[jc];
            float nn = pmr[LOD + jc];
            float uu = cur[jc];
            float ll = clr[jc];
            float ss = csr[jc];
            w_m[z] = ok ? mm : 0.0f;
            w_n[z] = ok ? nn : 0.0f;
            w_u[z] = ok ? uu : 0.0f;
            w_l[z] = ok ? ll : 0.0f;
            w_s[z] = ok ? ss : 0.0f;
        }
    }

    // ---------------- mixing (scalar loads) + banded products --------------
    float onm[2], onl[2], ouv[2], olv[2], osv[2];
    #pragma unroll
    for (int rr = 0; rr < 2; ++rr) {
        const int riu = 2 * wv + rr;                    // wave-uniform
        const int iu  = i0 + riu;
        const int iuc = (iu < LOD) ? iu : LOD - 1;      // rg7: garbage, skipped

        const float* tpg = ws + (size_t)iuc * TMBG_STRIDE;
        v2f t2[14];
        #pragma unroll
        for (int z = 0; z < 14; ++z) t2[z] = (v2f){0.f, 0.f};
        #pragma unroll
        for (int k = 0; k < NB; ++k) {
            v2f c2 = {cf[k], cf[k]};                    // splat: free via op_sel
            #pragma unroll
            for (int jo = 0; jo < 7; ++jo) {
                v2f w01 = *(const v2f*)(tpg + k * 28 + jo * 4);      // s_load
                v2f w23 = *(const v2f*)(tpg + k * 28 + jo * 4 + 2);  // s_load
                t2[2 * jo]     = FMA2(c2, w01, t2[2 * jo]);
                t2[2 * jo + 1] = FMA2(c2, w23, t2[2 * jo + 1]);
            }
        }
        t2[6].x += 1.0f;     // + eye on t11 at jo == 3 (m=0)
        t2[7].y += 1.0f;     // + eye on t22 at jo == 3 (m=3)

        float nmu = 0.f, nml = 0.f, ncuv = 0.f, nclv = 0.f, ncsv = 0.f;
        #pragma unroll
        for (int jo = 0; jo < 7; ++jo) {
            float m_ = w_m[jo + rr];                    // static index (0..7)
            float n_ = w_n[jo + rr];
            float u_ = w_u[jo + rr];
            float l_ = w_l[jo + rr];
            float s_ = w_s[jo + rr];
            float A  = t2[2 * jo].x,     Bv = t2[2 * jo].y;
            float C  = t2[2 * jo + 1].x, D  = t2[2 * jo + 1].y;
            nmu = fmaf(A, m_, nmu);  nmu = fmaf(Bv, n_, nmu);
            nml = fmaf(C, m_, nml);  nml = fmaf(D, n_, nml);
            float e1 = fmaf(Bv, s_, A * u_);
            float e2 = fmaf(Bv, l_, A * s_);
            float f1 = fmaf(D, s_, C * u_);
            float f2 = fmaf(D, l_, C * s_);
            ncuv = fmaf(A, e1, ncuv);  ncuv = fmaf(Bv, e2, ncuv);
            nclv = fmaf(C, f1, nclv);  nclv = fmaf(D, f2, nclv);
            ncsv = fmaf(C, e1, ncsv);  ncsv = fmaf(D, e2, ncsv);
        }
        ncuv += elup1f(log_noise[iuc]);
        nclv += elup1f(log_noise[LOD + iuc]);
        nmu  += (rr == 0) ? ctl0 : ctl1;
        nml  += (rr == 0) ? ctl2 : ctl3;
        onm[rr] = nmu; onl[rr] = nml; ouv[rr] = ncuv; olv[rr] = nclv; osv[rr] = ncsv;
    }

    // ---------------- ost staging + coalesced float4 flush -----------------
    #pragma unroll
    for (int rr = 0; rr < 2; ++rr) {
        const int ri = 2 * wv + rr;
        ost[0 * OST_PLANE + ri * 65 + lane] = onm[rr];
        ost[1 * OST_PLANE + ri * 65 + lane] = onl[rr];
        ost[2 * OST_PLANE + ri * 65 + lane] = ouv[rr];
        ost[3 * OST_PLANE + ri * 65 + lane] = olv[rr];
        ost[4 * OST_PLANE + ri * 65 + lane] = osv[rr];
    }
    __syncthreads();   // the ONLY barrier

    // float4 flush: 640 stores total, 16B-aligned (i0 % 8 == 0)
    for (int idx = tid; idx < 5 * 64 * 2; idx += 256) {
        int q   = idx & 1;
        int blc = (idx >> 1) & 63;
        int t5  = idx >> 7;
        if (i0 + q * 4 + 3 >= LOD) continue;     // only rg7, q=1
        int bb = b0 + blc;
        int ro = q * 4;
        float4 v;
        v.x = ost[t5 * OST_PLANE + (ro + 0) * 65 + blc];
        v.y = ost[t5 * OST_PLANE + (ro + 1) * 65 + blc];
        v.z = ost[t5 * OST_PLANE + (ro + 2) * 65 + blc];
        v.w = ost[t5 * OST_PLANE + (ro + 3) * 65 + blc];
        float* bp;
        if (t5 == 0)      bp = out + bb * LSD + i0;
        else if (t5 == 1) bp = out + bb * LSD + LOD + i0;
        else if (t5 == 2) bp = out + NM_SZ + bb * LOD + i0;
        else if (t5 == 3) bp = out + NM_SZ + NC_SZ + bb * LOD + i0;
        else              bp = out + NM_SZ + 2 * NC_SZ + bb * LOD + i0;
        *(float4*)(bp + ro) = v;
    }
}

extern "C" void kernel_launch(void* const* d_in, const int* in_sizes, int n_in,
                              void* d_out, int out_size, void* d_ws, size_t ws_size,
                              hipStream_t stream) {
    (void)in_sizes; (void)n_in; (void)out_size; (void)ws_size;
    const float* pm        = (const float*)d_in[0];
    const float* cu        = (const float*)d_in[1];
    const float* cl        = (const float*)d_in[2];
    const float* cs        = (const float*)d_in[3];
    const float* action    = (const float*)d_in[4];
    const float* tm11      = (const float*)d_in[5];
    const float* tm12      = (const float*)d_in[6];
    const float* tm21      = (const float*)d_in[7];
    const float* tm22      = (const float*)d_in[8];
    const float* log_noise = (const float*)d_in[9];
    const float* w_coef    = (const float*)d_in[10];
    const float* b_coef    = (const float*)d_in[11];
    const float* w_c1      = (const float*)d_in[12];
    const float* b_c1      = (const float*)d_in[13];
    const float* w_c2      = (const float*)d_in[14];
    const float* b_c2      = (const float*)d_in[15];

    float* ws = (float*)d_ws;   // 1132800 floats = 4.53 MB

    hipLaunchKernelGGL(k_prep, dim3(1024 + TMBG_FLOATS / 256), dim3(256), 0, stream,
                       pm, action, tm11, tm12, tm21, tm22,
                       w_coef, b_coef, w_c1, b_c1, w_c2, b_c2, ws);

    hipLaunchKernelGGL(k_main, dim3(1024), dim3(256), 0, stream,
                       pm, cu, cl, cs, log_noise, ws, (float*)d_out);
}

// Round 13
// 116.036 us; speedup vs baseline: 1.2425x; 1.2425x over previous
//
#include <hip/hip_runtime.h>
#include <math.h>

// Problem constants
#define BATCH 8192
#define LOD 60
#define LSD 120
#define AD 10
#define NB 15
#define BW 3
#define H 60

// Output layout (floats)
#define NM_SZ (BATCH * LSD)   // next_mean 983040
#define NC_SZ (BATCH * LOD)   // 491520 each for ncu/ncl/ncs

// Banded tm pack in workspace: [i][k][jo][m], row stride 448 floats (1792 B,
// 64B-aligned) so the compiler can batch s_load_dwordx8/x16.
#define TMBG_STRIDE 448
#define TMBG_ROW 420                  // NB * 7 * 4 valid floats per row
#define TMBG_FLOATS (LOD * TMBG_STRIDE)   // 26880

// Geometry: 128 batch-groups (64 batches) x 8 row-groups (8 rows) = 1024 blocks.
#define RGS 8
#define RG_ROWS 8
#define NJJ 16                        // 8 + 2*BW = 14, padded to pow2
#define VSJ 65
#define VSV (NJJ * VSJ)               // 1040 floats per staged plane
#define VS_FLOATS (5 * VSV)           // 5200 @ ovl[0]
// region X @ 5200: phase A/B = coef(960)+hid(3900)=4860; phase D/E = ost(2600)
#define COEF_OFF VS_FLOATS
#define HID_OFF (VS_FLOATS + NB * 64)
#define OST_OFF VS_FLOATS
#define OST_PLANE (RG_ROWS * 65)      // 520
#define OVL_FLOATS (VS_FLOATS + 4860) // 10060 floats = 40.24 KB -> 4 blocks/CU

typedef float v2f __attribute__((ext_vector_type(2)));
#define FMA2(a, b, c) __builtin_elementwise_fma((a), (b), (c))

__device__ __forceinline__ float elup1f(float x) {
    return x < 0.0f ? __expf(x) : x + 1.0f;
}

// ---------------------------------------------------------------------------
// Prepass: banded tm pack -> workspace (26880 floats, 105 blocks)
// ---------------------------------------------------------------------------
__global__ __launch_bounds__(256) void k_pack(
    const float* __restrict__ tm11, const float* __restrict__ tm12,
    const float* __restrict__ tm21, const float* __restrict__ tm22,
    float* __restrict__ tmbg)
{
    int idx = blockIdx.x * 256 + threadIdx.x;
    if (idx >= TMBG_FLOATS) return;
    int i = idx / TMBG_STRIDE;
    int r = idx - i * TMBG_STRIDE;
    float val = 0.0f;
    if (r < TMBG_ROW) {
        int k  = r / 28;
        int z  = r - k * 28;
        int jo = z >> 2;
        int m  = z & 3;
        int j  = i - BW + jo;
        const float* tmm = (m == 0) ? tm11 : (m == 1) ? tm12 : (m == 2) ? tm21 : tm22;
        if (j >= 0 && j < LOD) val = tmm[k * (LOD * LOD) + i * LOD + j];
    }
    tmbg[idx] = val;
}

// ---------------------------------------------------------------------------
// Main fused kernel (3 barriers; mixing weights via uniform scalar loads)
// ---------------------------------------------------------------------------
__global__ __launch_bounds__(256, 4) void k_fused(
    const float* __restrict__ pm, const float* __restrict__ cu,
    const float* __restrict__ cl, const float* __restrict__ cs,
    const float* __restrict__ action,
    const float* __restrict__ log_noise,
    const float* __restrict__ w_coef, const float* __restrict__ b_coef,
    const float* __restrict__ w_c1, const float* __restrict__ b_c1,
    const float* __restrict__ w_c2, const float* __restrict__ b_c2,
    const float* __restrict__ tmbg,
    float* __restrict__ out)
{
    __shared__ __align__(16) float ovl[OVL_FLOATS];  // 40.24 KB

    const int tid  = threadIdx.x;
    const int lane = tid & 63;
    const int wv   = __builtin_amdgcn_readfirstlane(tid >> 6);

    // XCD-grouped swizzle: the 8 rg-blocks of one bg share one XCD's L2.
    const int bid  = blockIdx.x;            // 1024 = 8 XCDs * 128
    const int xcd  = bid & 7;
    const int slot = bid >> 3;              // 0..127
    const int bg   = xcd * 16 + (slot >> 3);
    const int rg   = slot & 7;
    const int b0   = bg * 64;
    const int i0   = rg * RG_ROWS;

    float* vsb   = ovl;                  // [v][jj][b], stride 65
    float* coefL = ovl + COEF_OFF;       // phase A/B only
    float* hid_s = ovl + HID_OFF;        // phase A/B only

    // ---------------- T14: issue vs loads at the very top ------------------
    float vr[20];
    {
        const int jj  = tid & 15;
        const int j   = i0 - BW + jj;
        const bool jok = (j >= 0) && (j < LOD);
        #pragma unroll
        for (int z = 0; z < 20; ++z) {
            const int idx = z * 256 + tid;
            const int blc = (idx >> 4) & 63;
            const int bb  = b0 + blc;
            float val = 0.0f;
            if (jok) {
                const int v = z >> 2;                  // compile-time per z
                if (v == 0)      val = pm[bb * LSD + j];
                else if (v == 1) val = pm[bb * LSD + LOD + j];
                else if (v == 2) val = cu[bb * LOD + j];
                else if (v == 3) val = cl[bb * LOD + j];
                else             val = cs[bb * LOD + j];
            }
            vr[z] = val;
        }
    }

    // ---------------- phase A: logits + shared hidden layer ----------------
    {
        const int k0 = wv, k1 = wv + 4, k2 = wv + 8;
        const int k3 = (wv < 3) ? wv + 12 : 14;     // wave 3: dummy stream
        const float4* pmv = (const float4*)(pm + (size_t)(b0 + lane) * LSD);
        const float4* w0 = (const float4*)(w_coef + k0 * LSD);
        const float4* w1 = (const float4*)(w_coef + k1 * LSD);
        const float4* w2 = (const float4*)(w_coef + k2 * LSD);
        const float4* w3 = (const float4*)(w_coef + k3 * LSD);
        v2f a0 = {0.f, 0.f}, a1 = {0.f, 0.f}, a2 = {0.f, 0.f}, a3 = {0.f, 0.f};
        #pragma unroll 6
        for (int d = 0; d < LSD / 4; ++d) {
            float4 p = pmv[d];
            v2f plo = {p.x, p.y}, phi = {p.z, p.w};   // adjacent regs: zero-move pk
            float4 u0 = w0[d], u1 = w1[d], u2 = w2[d], u3 = w3[d];
            a0 = FMA2(plo, ((v2f){u0.x, u0.y}), a0);
            a0 = FMA2(phi, ((v2f){u0.z, u0.w}), a0);
            a1 = FMA2(plo, ((v2f){u1.x, u1.y}), a1);
            a1 = FMA2(phi, ((v2f){u1.z, u1.w}), a1);
            a2 = FMA2(plo, ((v2f){u2.x, u2.y}), a2);
            a2 = FMA2(phi, ((v2f){u2.z, u2.w}), a2);
            a3 = FMA2(plo, ((v2f){u3.x, u3.y}), a3);
            a3 = FMA2(phi, ((v2f){u3.z, u3.w}), a3);
        }
        coefL[k0 * 64 + lane] = a0.x + a0.y + b_coef[k0];
        coefL[k1 * 64 + lane] = a1.x + a1.y + b_coef[k1];
        coefL[k2 * 64 + lane] = a2.x + a2.y + b_coef[k2];
        if (wv < 3) coefL[k3 * 64 + lane] = a3.x + a3.y + b_coef[k3];
    }
    {   // hidden layer, shared: wave wv owns h in [15wv, 15wv+15)
        v2f av2[5];
        const float2* a2p = (const float2*)(action + (size_t)(b0 + lane) * AD);
        #pragma unroll
        for (int z = 0; z < 5; ++z) { float2 t2 = a2p[z]; av2[z] = (v2f){t2.x, t2.y}; }
        #pragma unroll
        for (int q = 0; q < 15; ++q) {
            int h = wv * 15 + q;
            v2f acc2 = {0.f, 0.f};
            #pragma unroll
            for (int z = 0; z < 5; ++z)
                acc2 = FMA2(av2[z], *(const v2f*)(w_c1 + h * AD + 2 * z), acc2);
            float acc = acc2.x + acc2.y + b_c1[h];
            hid_s[h * 65 + lane] = fmaxf(acc, 0.0f);
        }
    }
    __syncthreads();   // bar1: logits + hidden visible

    // ---------------- phase B: softmax + control (reads coef/hid) ----------
    float cf[NB];
    {
        float mx = -1e30f;
        #pragma unroll
        for (int k = 0; k < NB; ++k) { cf[k] = coefL[k * 64 + lane]; mx = fmaxf(mx, cf[k]); }
        float sm = 0.0f;
        #pragma unroll
        for (int k = 0; k < NB; ++k) { cf[k] = __expf(cf[k] - mx); sm += cf[k]; }
        float inv = 1.0f / sm;
        #pragma unroll
        for (int k = 0; k < NB; ++k) cf[k] *= inv;
    }
    const int r0g = i0 + 2 * wv;
    const int c0  = (r0g < LOD) ? r0g : LOD - 1;        // rg7/wv3 clamp
    const int c1  = (r0g + 1 < LOD) ? r0g + 1 : LOD - 1;
    float ctl0 = b_c2[c0], ctl1 = b_c2[c1];
    float ctl2 = b_c2[LOD + c0], ctl3 = b_c2[LOD + c1];
    #pragma unroll 4
    for (int h = 0; h < H; ++h) {
        float hv = hid_s[h * 65 + lane];                // lane-stride-1
        ctl0 = fmaf(hv, w_c2[c0 * H + h], ctl0);        // uniform -> s_load
        ctl1 = fmaf(hv, w_c2[c1 * H + h], ctl1);
        ctl2 = fmaf(hv, w_c2[(LOD + c0) * H + h], ctl2);
        ctl3 = fmaf(hv, w_c2[(LOD + c1) * H + h], ctl3);
    }

    // ---------------- phase C: vs LDS writes (region disjoint from X) ------
    {
        const int jj = tid & 15;
        #pragma unroll
        for (int z = 0; z < 20; ++z) {
            const int idx = z * 256 + tid;
            const int blc = (idx >> 4) & 63;
            vsb[(z >> 2) * VSV + jj * VSJ + blc] = vr[z];   // 2-way alias: free
        }
    }
    __syncthreads();   // bar2: vs staged; all coef/hid reads done

    // ---------------- phase D: mixing (scalar loads) + banded products -----
    float onm[2], onl[2], ouv[2], olv[2], osv[2];
    #pragma unroll
    for (int rr = 0; rr < 2; ++rr) {
        const int riu = 2 * wv + rr;                    // wave-uniform
        const int iu  = i0 + riu;
        const int iuc = (iu < LOD) ? iu : LOD - 1;      // rg7: garbage row, skipped

        // mixing: weights via uniform scalar loads on the SMEM pipe
        const float* tpg = tmbg + (size_t)iuc * TMBG_STRIDE;
        v2f t2[14];
        #pragma unroll
        for (int z = 0; z < 14; ++z) t2[z] = (v2f){0.f, 0.f};
        #pragma unroll
        for (int k = 0; k < NB; ++k) {
            v2f c2 = {cf[k], cf[k]};                    // splat: free via op_sel
            #pragma unroll
            for (int jo = 0; jo < 7; ++jo) {
                v2f w01 = *(const v2f*)(tpg + k * 28 + jo * 4);      // s_load
                v2f w23 = *(const v2f*)(tpg + k * 28 + jo * 4 + 2);  // s_load
                t2[2 * jo]     = FMA2(c2, w01, t2[2 * jo]);
                t2[2 * jo + 1] = FMA2(c2, w23, t2[2 * jo + 1]);
            }
        }
        t2[6].x += 1.0f;     // + eye on t11 at jo == 3 (m=0)
        t2[7].y += 1.0f;     // + eye on t22 at jo == 3 (m=3)

        // banded products: scalar form (round-5 proven codegen)
        float nmu = 0.f, nml = 0.f, ncuv = 0.f, nclv = 0.f, ncsv = 0.f;
        #pragma unroll
        for (int jo = 0; jo < 7; ++jo) {
            const int jj = riu + jo;                    // 0..13 < NJJ
            float m_ = vsb[0 * VSV + jj * VSJ + lane];
            float n_ = vsb[1 * VSV + jj * VSJ + lane];
            float u_ = vsb[2 * VSV + jj * VSJ + lane];
            float l_ = vsb[3 * VSV + jj * VSJ + lane];
            float s_ = vsb[4 * VSV + jj * VSJ + lane];
            float A  = t2[2 * jo].x,     Bv = t2[2 * jo].y;
            float C  = t2[2 * jo + 1].x, D  = t2[2 * jo + 1].y;
            nmu = fmaf(A, m_, nmu);  nmu = fmaf(Bv, n_, nmu);
            nml = fmaf(C, m_, nml);  nml = fmaf(D, n_, nml);
            float e1 = fmaf(Bv, s_, A * u_);
            float e2 = fmaf(Bv, l_, A * s_);
            float f1 = fmaf(D, s_, C * u_);
            float f2 = fmaf(D, l_, C * s_);
            ncuv = fmaf(A, e1, ncuv);  ncuv = fmaf(Bv, e2, ncuv);
            nclv = fmaf(C, f1, nclv);  nclv = fmaf(D, f2, nclv);
            ncsv = fmaf(C, e1, ncsv);  ncsv = fmaf(D, e2, ncsv);
        }
        ncuv += elup1f(log_noise[iuc]);
        nclv += elup1f(log_noise[LOD + iuc]);
        nmu  += (rr == 0) ? ctl0 : ctl1;
        nml  += (rr == 0) ? ctl2 : ctl3;
        onm[rr] = nmu; onl[rr] = nml; ouv[rr] = ncuv; olv[rr] = nclv; osv[rr] = ncsv;
    }

    // ---------------- phase E: ost staging (overlays coef/hid) -------------
    // All reads of region X (coefL/hid_s) finished before bar2 -> safe now.
    float* ost = ovl + OST_OFF;
    #pragma unroll
    for (int rr = 0; rr < 2; ++rr) {
        const int ri = 2 * wv + rr;
        ost[0 * OST_PLANE + ri * 65 + lane] = onm[rr];
        ost[1 * OST_PLANE + ri * 65 + lane] = onl[rr];
        ost[2 * OST_PLANE + ri * 65 + lane] = ouv[rr];
        ost[3 * OST_PLANE + ri * 65 + lane] = olv[rr];
        ost[4 * OST_PLANE + ri * 65 + lane] = osv[rr];
    }
    __syncthreads();   // bar3

    // float4 flush: 640 stores total, 16B-aligned (i0 % 8 == 0)
    for (int idx = tid; idx < 5 * 64 * 2; idx += 256) {
        int q   = idx & 1;
        int blc = (idx >> 1) & 63;
        int t5  = idx >> 7;
        if (i0 + q * 4 + 3 >= LOD) continue;     // only rg7, q=1
        int bb = b0 + blc;
        int ro = q * 4;
        float4 v;
        v.x = ost[t5 * OST_PLANE + (ro + 0) * 65 + blc];
        v.y = ost[t5 * OST_PLANE + (ro + 1) * 65 + blc];
        v.z = ost[t5 * OST_PLANE + (ro + 2) * 65 + blc];
        v.w = ost[t5 * OST_PLANE + (ro + 3) * 65 + blc];
        float* bp;
        if (t5 == 0)      bp = out + bb * LSD + i0;
        else if (t5 == 1) bp = out + bb * LSD + LOD + i0;
        else if (t5 == 2) bp = out + NM_SZ + bb * LOD + i0;
        else if (t5 == 3) bp = out + NM_SZ + NC_SZ + bb * LOD + i0;
        else              bp = out + NM_SZ + 2 * NC_SZ + bb * LOD + i0;
        *(float4*)(bp + ro) = v;
    }
}

extern "C" void kernel_launch(void* const* d_in, const int* in_sizes, int n_in,
                              void* d_out, int out_size, void* d_ws, size_t ws_size,
                              hipStream_t stream) {
    (void)in_sizes; (void)n_in; (void)out_size; (void)ws_size;
    const float* pm        = (const float*)d_in[0];
    const float* cu        = (const float*)d_in[1];
    const float* cl        = (const float*)d_in[2];
    const float* cs        = (const float*)d_in[3];
    const float* action    = (const float*)d_in[4];
    const float* tm11      = (const float*)d_in[5];
    const float* tm12      = (const float*)d_in[6];
    const float* tm21      = (const float*)d_in[7];
    const float* tm22      = (const float*)d_in[8];
    const float* log_noise = (const float*)d_in[9];
    const float* w_coef    = (const float*)d_in[10];
    const float* b_coef    = (const float*)d_in[11];
    const float* w_c1      = (const float*)d_in[12];
    const float* b_c1      = (const float*)d_in[13];
    const float* w_c2      = (const float*)d_in[14];
    const float* b_c2      = (const float*)d_in[15];

    float* tmbg = (float*)d_ws;   // 26880 floats = 107.5 KB

    hipLaunchKernelGGL(k_pack, dim3((TMBG_FLOATS + 255) / 256), dim3(256), 0, stream,
                       tm11, tm12, tm21, tm22, tmbg);

    hipLaunchKernelGGL(k_fused, dim3(1024), dim3(256), 0, stream,
                       pm, cu, cl, cs, action, log_noise,
                       w_coef, b_coef, w_c1, b_c1, w_c2, b_c2, tmbg,
                       (float*)d_out);
}